// Round 13
// baseline (639.012 us; speedup 1.0000x reference)
//
#include <hip/hip_runtime.h>

typedef short bf16x8 __attribute__((ext_vector_type(8)));
typedef float f32x4 __attribute__((ext_vector_type(4)));
typedef unsigned short u16;

#define NNODE 196608
#define FF 32
#define COLS 256   // UP * OUT_FEATURES
#define KTOT 288   // KK * FF
#define WELEMS (COLS * KTOT)   // 73728 elems = 144 KB bf16
#define TPB 6                  // tiles per block (1536 / 256)

__device__ __forceinline__ u16 f2bf(float f) {
    unsigned u = __builtin_bit_cast(unsigned, f);
    return (u16)((u + 0x7fffu + ((u >> 16) & 1u)) >> 16);  // RTNE
}

// prep 1: x (2,N,32) f32 -> xb2 bf16 INTERLEAVED: xb2[node][0:32]=t0 feats,
// xb2[node][32:64]=t1 feats -> one 128-B line per node (gather = 1 line).
__global__ void cvt_x(const float* __restrict__ x, u16* __restrict__ xb2, int n8) {
    int i = blockIdx.x * blockDim.x + threadIdx.x;
    if (i >= n8) return;
    int og   = i * 8;           // output element index (u16 units)
    int node = og >> 6;
    int rem  = og & 63;
    int s    = rem >> 5;        // t-slice
    int f0   = rem & 31;        // feature start (0,8,16,24)
    const float* src = x + ((size_t)s * NNODE + node) * FF + f0;
    f32x4 v0 = *(const f32x4*)src;
    f32x4 v1 = *(const f32x4*)(src + 4);
    union { u16 h[8]; bf16x8 v; } r;
    #pragma unroll
    for (int j = 0; j < 4; ++j) r.h[j] = f2bf(v0[j]);
    #pragma unroll
    for (int j = 0; j < 4; ++j) r.h[4 + j] = f2bf(v1[j]);
    *((bf16x8*)xb2 + i) = r.v;
}

// prep 2: W (K,F,UP,O) f32 -> Wt bf16, MFMA fragment-linear:
// Wt[f*512 + lane*8 + e] = W[kf][c], f = kk*16+ct, c = ct*16+(lane&15),
// kf = kk*32 + (lane>>4)*8 + e. Wave ds_read_b128 of a frag: lane-linear.
__global__ void cvt_w(const float* __restrict__ W, u16* __restrict__ Wt) {
    int gid = blockIdx.x * 256 + threadIdx.x;   // 73728 total
    int f      = gid >> 9;
    int within = gid & 511;
    int lane   = within >> 3;
    int e      = within & 7;
    int kk = f >> 4, ct = f & 15;
    int cl = lane & 15, q = lane >> 4;
    int c  = ct * 16 + cl;
    int kf = kk * 32 + q * 8 + e;
    Wt[gid] = f2bf(W[(size_t)kf * COLS + c]);
}

// main: EXACTLY R8 (best, 143.9 us) minus the per-tile s_barrier.
// R8's barrier had no data-sharing purpose (each wave gathers private
// nodes, C=1 via in-wave t-fusion) but phase-locked all 8 waves, making
// the pipes (HBM stores / LDS reads / MFMA / TA gathers) burst in
// lockstep -> additive timing (57+34+23+23 us ~= observed 128). Free-
// running waves let a SIMD's two waves pair compute-phase with
// store/gather-phase. #pragma unroll 1 keeps the tile loop a real loop
// (scheduling boundary -> no cross-tile seam state / spill, R6/R7 lesson).
__global__ __launch_bounds__(512, 2) void updown_main(
    const u16* __restrict__ xb2, const u16* __restrict__ Wt,
    const int* __restrict__ adjc, const float* __restrict__ bias,
    float* __restrict__ out)
{
    __shared__ __align__(16) u16 wlds[WELEMS];   // 144 KB, read-only after load
    __shared__ __align__(16) float blds[COLS];   // 1 KB bias

    const int tid = threadIdx.x;

    #pragma unroll
    for (int i = 0; i < 18; ++i)
        *(bf16x8*)(wlds + i * 4096 + tid * 8) =
            *(const bf16x8*)(Wt + i * 4096 + tid * 8);
    if (tid < 64) ((f32x4*)blds)[tid] = ((const f32x4*)bias)[tid];
    __syncthreads();   // the only barrier

    const int w    = tid >> 6;
    const int lane = tid & 63;
    const int l15  = lane & 15;
    const int q    = lane >> 4;
    const u16* wbase = wlds + lane * 8;   // + kk*8192 + ct*512
    const float* bb  = blds + q * 4;      // + ct*16

    const int node0 = blockIdx.x * (TPB * 128) + w * 16 + l15;

    #pragma unroll 1
    for (int tt = 0; tt < TPB; ++tt) {
        const int node  = node0 + tt * 128;
        const int* arow = adjc + (size_t)node * 9;

        // tile prologue: 2 gathers in flight + idx for the third
        int i0 = arow[0];
        int i1 = arow[1];
        const u16* g0 = xb2 + (size_t)i0 * 64 + q * 8;
        bf16x8 aC0 = *(const bf16x8*)g0;
        bf16x8 aC1 = *(const bf16x8*)(g0 + 32);
        const u16* g1 = xb2 + (size_t)i1 * 64 + q * 8;
        bf16x8 aN0 = *(const bf16x8*)g1;
        bf16x8 aN1 = *(const bf16x8*)(g1 + 32);
        int idxP = arow[2];   // idx one iteration ahead of its gather

        // acc init = bias (lgkm counter — doesn't touch the vmcnt FIFO)
        f32x4 acc0[16], acc1[16];
        #pragma unroll
        for (int ct = 0; ct < 16; ++ct) {
            f32x4 bq = *(const f32x4*)(bb + ct * 16);
            acc0[ct] = bq;
            acc1[ct] = bq;
        }

        #pragma unroll
        for (int kk = 0; kk < 9; ++kk) {
            bf16x8 aNN0, aNN1;
            if (kk < 7) {   // gather kk+2 using idx loaded last iteration
                const u16* g2 = xb2 + (size_t)idxP * 64 + q * 8;
                aNN0 = *(const bf16x8*)g2;
                aNN1 = *(const bf16x8*)(g2 + 32);
            }
            if (kk < 6) idxP = arow[kk + 3];   // idx for next iteration's gather

            const u16* wk = wbase + kk * 8192;
            #pragma unroll
            for (int ct = 0; ct < 16; ++ct) {
                bf16x8 af = *(const bf16x8*)(wk + ct * 512);
                acc0[ct] = __builtin_amdgcn_mfma_f32_16x16x32_bf16(af, aC0, acc0[ct], 0, 0, 0);
                acc1[ct] = __builtin_amdgcn_mfma_f32_16x16x32_bf16(af, aC1, acc1[ct], 0, 0, 0);
            }
            if (kk < 8) { aC0 = aN0; aC1 = aN1; }
            if (kk < 7) { aN0 = aNN0; aN1 = aNN1; }
        }

        // stores: lane-contiguous f32x4, dense full-line coverage
        float* o0 = out + (size_t)node * COLS + q * 4;
        float* o1 = o0 + (size_t)NNODE * COLS;
        #pragma unroll
        for (int ct = 0; ct < 16; ++ct) {
            *(f32x4*)(o0 + ct * 16) = acc0[ct];
            *(f32x4*)(o1 + ct * 16) = acc1[ct];
        }
        // NO barrier: waves free-run and phase-stagger (R13 single-variable
        // test vs R8). No inter-wave data dependence exists in this loop.
    }
}

extern "C" void kernel_launch(void* const* d_in, const int* in_sizes, int n_in,
                              void* d_out, int out_size, void* d_ws, size_t ws_size,
                              hipStream_t stream) {
    const float* x    = (const float*)d_in[0];
    const int*   adjc = (const int*)d_in[1];
    const float* W    = (const float*)d_in[2];
    const float* b    = (const float*)d_in[3];
    float* out = (float*)d_out;

    u16* xb2 = (u16*)d_ws;                           // 196608*64 bf16 = 25.2 MB
    u16* Wt  = xb2 + (size_t)NNODE * 64;             // 73728 bf16 = 144 KB

    cvt_x<<<dim3(6144), dim3(256), 0, stream>>>(x, xb2, 1572864);
    cvt_w<<<dim3(288), dim3(256), 0, stream>>>(W, Wt);
    updown_main<<<dim3(256), dim3(512), 0, stream>>>(xb2, Wt, adjc, b, out);
}

// Round 14
// 167.127 us; speedup vs baseline: 3.8235x; 3.8235x over previous
//
#include <hip/hip_runtime.h>

typedef short bf16x8 __attribute__((ext_vector_type(8)));
typedef float f32x4 __attribute__((ext_vector_type(4)));
typedef unsigned short u16;

#define NNODE 196608
#define FF 32
#define COLS 256   // UP * OUT_FEATURES
#define KTOT 288   // KK * FF
#define WELEMS (COLS * KTOT)   // 73728 elems = 144 KB bf16
#define TPB 6                  // tiles per block (1536 / 256)

__device__ __forceinline__ u16 f2bf(float f) {
    unsigned u = __builtin_bit_cast(unsigned, f);
    return (u16)((u + 0x7fffu + ((u >> 16) & 1u)) >> 16);  // RTNE
}

// prep 1: x (2,N,32) f32 -> xb2 bf16 INTERLEAVED: xb2[node][0:32]=t0 feats,
// xb2[node][32:64]=t1 feats -> one 128-B line per node (gather = 1 line).
// NORMAL (allocating) stores on purpose: xb2 should be L3-resident for main.
__global__ void cvt_x(const float* __restrict__ x, u16* __restrict__ xb2, int n8) {
    int i = blockIdx.x * blockDim.x + threadIdx.x;
    if (i >= n8) return;
    int og   = i * 8;           // output element index (u16 units)
    int node = og >> 6;
    int rem  = og & 63;
    int s    = rem >> 5;        // t-slice
    int f0   = rem & 31;        // feature start (0,8,16,24)
    const float* src = x + ((size_t)s * NNODE + node) * FF + f0;
    f32x4 v0 = *(const f32x4*)src;
    f32x4 v1 = *(const f32x4*)(src + 4);
    union { u16 h[8]; bf16x8 v; } r;
    #pragma unroll
    for (int j = 0; j < 4; ++j) r.h[j] = f2bf(v0[j]);
    #pragma unroll
    for (int j = 0; j < 4; ++j) r.h[4 + j] = f2bf(v1[j]);
    *((bf16x8*)xb2 + i) = r.v;
}

// prep 2: W (K,F,UP,O) f32 -> Wt bf16, MFMA fragment-linear:
// Wt[f*512 + lane*8 + e] = W[kf][c], f = kk*16+ct, c = ct*16+(lane&15),
// kf = kk*32 + (lane>>4)*8 + e. Wave ds_read_b128 of a frag: lane-linear.
__global__ void cvt_w(const float* __restrict__ W, u16* __restrict__ Wt) {
    int gid = blockIdx.x * 256 + threadIdx.x;   // 73728 total
    int f      = gid >> 9;
    int within = gid & 511;
    int lane   = within >> 3;
    int e      = within & 7;
    int kk = f >> 4, ct = f & 15;
    int cl = lane & 15, q = lane >> 4;
    int c  = ct * 16 + cl;
    int kf = kk * 32 + q * 8 + e;
    Wt[gid] = f2bf(W[(size_t)kf * COLS + c]);
}

// main: EXACTLY R8 (best, 143.9 us) with ONE change: output stores are
// NON-TEMPORAL (evict-first). R13's counters showed the gathers (226 MB of
// 128-B lines) were MISSING L3 because the 402 MB output stream evicts the
// 25 MB xb2 from Infinity Cache -> R8 is memory-bound on evicted-gather
// HBM traffic (402+226+30 ~= 660 MB @ ~5.5 TB/s ~= measured ~120 us main).
// NT stores keep xb2 L3-resident -> gathers become L3 hits -> ~430 MB HBM.
// (R4's NT regression was 128 SCALAR nt stores — issue-bound confound;
// here stores stay 32 x f32x4.) Everything else byte-identical to R8:
// unrolled tile loop + per-tile raw s_barrier (load-bearing for codegen,
// R13 lesson), depth-2 spread gathers, no cross-seam state.
__global__ __launch_bounds__(512, 2) void updown_main(
    const u16* __restrict__ xb2, const u16* __restrict__ Wt,
    const int* __restrict__ adjc, const float* __restrict__ bias,
    float* __restrict__ out)
{
    __shared__ __align__(16) u16 wlds[WELEMS];   // 144 KB, read-only after load
    __shared__ __align__(16) float blds[COLS];   // 1 KB bias

    const int tid = threadIdx.x;

    #pragma unroll
    for (int i = 0; i < 18; ++i)
        *(bf16x8*)(wlds + i * 4096 + tid * 8) =
            *(const bf16x8*)(Wt + i * 4096 + tid * 8);
    if (tid < 64) ((f32x4*)blds)[tid] = ((const f32x4*)bias)[tid];
    __syncthreads();   // the only full barrier

    const int w    = tid >> 6;
    const int lane = tid & 63;
    const int l15  = lane & 15;
    const int q    = lane >> 4;
    const u16* wbase = wlds + lane * 8;   // + kk*8192 + ct*512
    const float* bb  = blds + q * 4;      // + ct*16

    const int node0 = blockIdx.x * (TPB * 128) + w * 16 + l15;

    for (int tt = 0; tt < TPB; ++tt) {
        const int node  = node0 + tt * 128;
        const int* arow = adjc + (size_t)node * 9;

        // tile prologue: 2 gathers in flight + idx for the third
        int i0 = arow[0];
        int i1 = arow[1];
        const u16* g0 = xb2 + (size_t)i0 * 64 + q * 8;
        bf16x8 aC0 = *(const bf16x8*)g0;
        bf16x8 aC1 = *(const bf16x8*)(g0 + 32);
        const u16* g1 = xb2 + (size_t)i1 * 64 + q * 8;
        bf16x8 aN0 = *(const bf16x8*)g1;
        bf16x8 aN1 = *(const bf16x8*)(g1 + 32);
        int idxP = arow[2];   // idx one iteration ahead of its gather

        // acc init = bias (lgkm counter — doesn't touch the vmcnt FIFO)
        f32x4 acc0[16], acc1[16];
        #pragma unroll
        for (int ct = 0; ct < 16; ++ct) {
            f32x4 bq = *(const f32x4*)(bb + ct * 16);
            acc0[ct] = bq;
            acc1[ct] = bq;
        }

        #pragma unroll
        for (int kk = 0; kk < 9; ++kk) {
            bf16x8 aNN0, aNN1;
            if (kk < 7) {   // gather kk+2 using idx loaded last iteration
                const u16* g2 = xb2 + (size_t)idxP * 64 + q * 8;
                aNN0 = *(const bf16x8*)g2;
                aNN1 = *(const bf16x8*)(g2 + 32);
            }
            if (kk < 6) idxP = arow[kk + 3];   // idx for next iteration's gather

            const u16* wk = wbase + kk * 8192;
            #pragma unroll
            for (int ct = 0; ct < 16; ++ct) {
                bf16x8 af = *(const bf16x8*)(wk + ct * 512);
                acc0[ct] = __builtin_amdgcn_mfma_f32_16x16x32_bf16(af, aC0, acc0[ct], 0, 0, 0);
                acc1[ct] = __builtin_amdgcn_mfma_f32_16x16x32_bf16(af, aC1, acc1[ct], 0, 0, 0);
            }
            if (kk < 8) { aC0 = aN0; aC1 = aN1; }
            if (kk < 7) { aN0 = aNN0; aN1 = aNN1; }
        }

        // stores: lane-contiguous f32x4, NON-TEMPORAL (evict-first: keep
        // xb2 resident in L2/L3 so next tiles' gathers hit cache)
        float* o0 = out + (size_t)node * COLS + q * 4;
        float* o1 = o0 + (size_t)NNODE * COLS;
        #pragma unroll
        for (int ct = 0; ct < 16; ++ct) {
            __builtin_nontemporal_store(acc0[ct], (f32x4*)(o0 + ct * 16));
            __builtin_nontemporal_store(acc1[ct], (f32x4*)(o1 + ct * 16));
        }

        // phase-lock the 8 waves; raw barrier: NO vmcnt drain
        __builtin_amdgcn_s_barrier();
    }
}

extern "C" void kernel_launch(void* const* d_in, const int* in_sizes, int n_in,
                              void* d_out, int out_size, void* d_ws, size_t ws_size,
                              hipStream_t stream) {
    const float* x    = (const float*)d_in[0];
    const int*   adjc = (const int*)d_in[1];
    const float* W    = (const float*)d_in[2];
    const float* b    = (const float*)d_in[3];
    float* out = (float*)d_out;

    u16* xb2 = (u16*)d_ws;                           // 196608*64 bf16 = 25.2 MB
    u16* Wt  = xb2 + (size_t)NNODE * 64;             // 73728 bf16 = 144 KB

    cvt_x<<<dim3(6144), dim3(256), 0, stream>>>(x, xb2, 1572864);
    cvt_w<<<dim3(288), dim3(256), 0, stream>>>(W, Wt);
    updown_main<<<dim3(256), dim3(512), 0, stream>>>(xb2, Wt, adjc, b, out);
}

// Round 15
// 142.175 us; speedup vs baseline: 4.4945x; 1.1755x over previous
//
#include <hip/hip_runtime.h>

typedef short bf16x8 __attribute__((ext_vector_type(8)));
typedef float f32x4 __attribute__((ext_vector_type(4)));
typedef unsigned short u16;

#define NNODE 196608
#define FF 32
#define COLS 256   // UP * OUT_FEATURES
#define KTOT 288   // KK * FF
#define WELEMS (COLS * KTOT)   // 73728 elems = 144 KB bf16
#define TPB 6                  // tiles per block (1536 / 256)

__device__ __forceinline__ u16 f2bf(float f) {
    unsigned u = __builtin_bit_cast(unsigned, f);
    return (u16)((u + 0x7fffu + ((u >> 16) & 1u)) >> 16);  // RTNE
}

// prep 1: x (2,N,32) f32 -> xb2 bf16 INTERLEAVED: xb2[node][0:32]=t0 feats,
// xb2[node][32:64]=t1 feats -> one 128-B line per node (gather = 1 line).
__global__ void cvt_x(const float* __restrict__ x, u16* __restrict__ xb2, int n8) {
    int i = blockIdx.x * blockDim.x + threadIdx.x;
    if (i >= n8) return;
    int og   = i * 8;           // output element index (u16 units)
    int node = og >> 6;
    int rem  = og & 63;
    int s    = rem >> 5;        // t-slice
    int f0   = rem & 31;        // feature start (0,8,16,24)
    const float* src = x + ((size_t)s * NNODE + node) * FF + f0;
    f32x4 v0 = *(const f32x4*)src;
    f32x4 v1 = *(const f32x4*)(src + 4);
    union { u16 h[8]; bf16x8 v; } r;
    #pragma unroll
    for (int j = 0; j < 4; ++j) r.h[j] = f2bf(v0[j]);
    #pragma unroll
    for (int j = 0; j < 4; ++j) r.h[4 + j] = f2bf(v1[j]);
    *((bf16x8*)xb2 + i) = r.v;
}

// prep 2: W (K,F,UP,O) f32 -> Wt bf16, MFMA fragment-linear:
// Wt[f*512 + lane*8 + e] = W[kf][c], f = kk*16+ct, c = ct*16+(lane&15),
// kf = kk*32 + (lane>>4)*8 + e. Wave ds_read_b128 of a frag: lane-linear.
__global__ void cvt_w(const float* __restrict__ W, u16* __restrict__ Wt) {
    int gid = blockIdx.x * 256 + threadIdx.x;   // 73728 total
    int f      = gid >> 9;
    int within = gid & 511;
    int lane   = within >> 3;
    int e      = within & 7;
    int kk = f >> 4, ct = f & 15;
    int cl = lane & 15, q = lane >> 4;
    int c  = ct * 16 + cl;
    int kf = kk * 32 + q * 8 + e;
    Wt[gid] = f2bf(W[(size_t)kf * COLS + c]);
}

// main: EXACTLY R8 (best, 143.9 us) with ONE change: gather pipeline is
// DEPTH-3 with ZERO extra registers. Three fixed stage buffers B0/B1/B2;
// step kk consumes B[kk%3] and refills the SAME buffer right after its
// MFMAs (issue-after-consume) for step kk+3 -> ~2.7 k-steps (~850+ cyc)
// of lead vs depth-2's ~600, covering HBM gather latency (~900 cyc, m126).
// Register count identical to R8's aC/aN/aNN chain -> no spill risk.
// Everything else byte-identical: plain f32x4 stores (NT is +20us slower,
// R4/R14), unrolled tile loop + per-tile raw s_barrier (load-bearing for
// codegen, R13), acc-init-from-bias, no cross-seam state (R6/R7).
__global__ __launch_bounds__(512, 2) void updown_main(
    const u16* __restrict__ xb2, const u16* __restrict__ Wt,
    const int* __restrict__ adjc, const float* __restrict__ bias,
    float* __restrict__ out)
{
    __shared__ __align__(16) u16 wlds[WELEMS];   // 144 KB, read-only after load
    __shared__ __align__(16) float blds[COLS];   // 1 KB bias

    const int tid = threadIdx.x;

    #pragma unroll
    for (int i = 0; i < 18; ++i)
        *(bf16x8*)(wlds + i * 4096 + tid * 8) =
            *(const bf16x8*)(Wt + i * 4096 + tid * 8);
    if (tid < 64) ((f32x4*)blds)[tid] = ((const f32x4*)bias)[tid];
    __syncthreads();   // the only full barrier

    const int w    = tid >> 6;
    const int lane = tid & 63;
    const int l15  = lane & 15;
    const int q    = lane >> 4;
    const u16* wbase = wlds + lane * 8;   // + kk*8192 + ct*512
    const float* bb  = blds + q * 4;      // + ct*16

    const int node0 = blockIdx.x * (TPB * 128) + w * 16 + l15;

    for (int tt = 0; tt < TPB; ++tt) {
        const int node  = node0 + tt * 128;
        const int* arow = adjc + (size_t)node * 9;

        // tile prologue: 3 gathers in flight (depth-3), idx for the 4th
        int i0 = arow[0];
        int i1 = arow[1];
        int i2 = arow[2];
        const u16* p0 = xb2 + (size_t)i0 * 64 + q * 8;
        const u16* p1 = xb2 + (size_t)i1 * 64 + q * 8;
        const u16* p2 = xb2 + (size_t)i2 * 64 + q * 8;
        bf16x8 B0t0 = *(const bf16x8*)p0, B0t1 = *(const bf16x8*)(p0 + 32);
        bf16x8 B1t0 = *(const bf16x8*)p1, B1t1 = *(const bf16x8*)(p1 + 32);
        bf16x8 B2t0 = *(const bf16x8*)p2, B2t1 = *(const bf16x8*)(p2 + 32);
        int idxP = arow[3];   // idx one step ahead of its gather issue

        // acc init = bias (lgkm counter — doesn't touch the vmcnt FIFO)
        f32x4 acc0[16], acc1[16];
        #pragma unroll
        for (int ct = 0; ct < 16; ++ct) {
            f32x4 bq = *(const f32x4*)(bb + ct * 16);
            acc0[ct] = bq;
            acc1[ct] = bq;
        }

        #pragma unroll
        for (int kk = 0; kk < 9; ++kk) {
            const int st = kk % 3;   // compile-time under full unroll
            bf16x8 a0 = (st == 0) ? B0t0 : (st == 1) ? B1t0 : B2t0;
            bf16x8 a1 = (st == 0) ? B0t1 : (st == 1) ? B1t1 : B2t1;

            const u16* wk = wbase + kk * 8192;
            #pragma unroll
            for (int ct = 0; ct < 16; ++ct) {
                bf16x8 af = *(const bf16x8*)(wk + ct * 512);
                acc0[ct] = __builtin_amdgcn_mfma_f32_16x16x32_bf16(af, a0, acc0[ct], 0, 0, 0);
                acc1[ct] = __builtin_amdgcn_mfma_f32_16x16x32_bf16(af, a1, acc1[ct], 0, 0, 0);
            }

            // refill the just-consumed stage for step kk+3 (issue-after-
            // consume: WAR on B regs keeps issue below the MFMAs)
            if (kk < 6) {
                const u16* g2 = xb2 + (size_t)idxP * 64 + q * 8;
                bf16x8 n0 = *(const bf16x8*)g2;
                bf16x8 n1 = *(const bf16x8*)(g2 + 32);
                if      (st == 0) { B0t0 = n0; B0t1 = n1; }
                else if (st == 1) { B1t0 = n0; B1t1 = n1; }
                else              { B2t0 = n0; B2t1 = n1; }
            }
            if (kk < 5) idxP = arow[kk + 4];
        }

        // stores: lane-contiguous f32x4, dense full-line coverage
        float* o0 = out + (size_t)node * COLS + q * 4;
        float* o1 = o0 + (size_t)NNODE * COLS;
        #pragma unroll
        for (int ct = 0; ct < 16; ++ct) {
            *(f32x4*)(o0 + ct * 16) = acc0[ct];
            *(f32x4*)(o1 + ct * 16) = acc1[ct];
        }

        // phase-lock the 8 waves; raw barrier: NO vmcnt drain
        __builtin_amdgcn_s_barrier();
    }
}

extern "C" void kernel_launch(void* const* d_in, const int* in_sizes, int n_in,
                              void* d_out, int out_size, void* d_ws, size_t ws_size,
                              hipStream_t stream) {
    const float* x    = (const float*)d_in[0];
    const int*   adjc = (const int*)d_in[1];
    const float* W    = (const float*)d_in[2];
    const float* b    = (const float*)d_in[3];
    float* out = (float*)d_out;

    u16* xb2 = (u16*)d_ws;                           // 196608*64 bf16 = 25.2 MB
    u16* Wt  = xb2 + (size_t)NNODE * 64;             // 73728 bf16 = 144 KB

    cvt_x<<<dim3(6144), dim3(256), 0, stream>>>(x, xb2, 1572864);
    cvt_w<<<dim3(288), dim3(256), 0, stream>>>(W, Wt);
    updown_main<<<dim3(256), dim3(512), 0, stream>>>(xb2, Wt, adjc, b, out);
}

// Round 16
// 141.779 us; speedup vs baseline: 4.5071x; 1.0028x over previous
//
#include <hip/hip_runtime.h>

typedef short bf16x8 __attribute__((ext_vector_type(8)));
typedef float f32x4 __attribute__((ext_vector_type(4)));
typedef unsigned short u16;

#define NNODE 196608
#define FF 32
#define COLS 256   // UP * OUT_FEATURES
#define KTOT 288   // KK * FF
#define WELEMS (COLS * KTOT)   // 73728 elems = 144 KB bf16
#define TPB 6                  // tiles per block (1536 / 256)
#define XBLKS 6144             // prep blocks for x

__device__ __forceinline__ u16 f2bf(float f) {
    unsigned u = __builtin_bit_cast(unsigned, f);
    return (u16)((u + 0x7fffu + ((u >> 16) & 1u)) >> 16);  // RTNE
}

// fused prep: blocks [0,6144) convert x -> xb2 (interleaved, one 128-B
// line per node: [0:32]=t0 feats, [32:64]=t1); blocks [6144,6432) convert
// W -> Wt in MFMA fragment-linear order:
//   Wt[f*512 + lane*8 + e] = W[kf][c], f = kk*16+ct, c = ct*16+(lane&15),
//   kf = kk*32 + (lane>>4)*8 + e  (wave ds_read_b128 of a frag: lane-linear)
__global__ void prep(const float* __restrict__ x, u16* __restrict__ xb2,
                     const float* __restrict__ W, u16* __restrict__ Wt) {
    if (blockIdx.x < XBLKS) {
        int i = blockIdx.x * blockDim.x + threadIdx.x;   // < 1572864
        int og   = i * 8;
        int node = og >> 6;
        int rem  = og & 63;
        int s    = rem >> 5;
        int f0   = rem & 31;
        const float* src = x + ((size_t)s * NNODE + node) * FF + f0;
        f32x4 v0 = *(const f32x4*)src;
        f32x4 v1 = *(const f32x4*)(src + 4);
        union { u16 h[8]; bf16x8 v; } r;
        #pragma unroll
        for (int j = 0; j < 4; ++j) r.h[j] = f2bf(v0[j]);
        #pragma unroll
        for (int j = 0; j < 4; ++j) r.h[4 + j] = f2bf(v1[j]);
        *((bf16x8*)xb2 + i) = r.v;
    } else {
        int gid = (blockIdx.x - XBLKS) * 256 + threadIdx.x;   // < 73728
        int f      = gid >> 9;
        int within = gid & 511;
        int lane   = within >> 3;
        int e      = within & 7;
        int kk = f >> 4, ct = f & 15;
        int cl = lane & 15, q = lane >> 4;
        int c  = ct * 16 + cl;
        int kf = kk * 32 + q * 8 + e;
        Wt[gid] = f2bf(W[(size_t)kf * COLS + c]);
    }
}

// main: R15 (best, 142.2 us) with tile-0's prologue (adjc row + 3 gather
// pairs) HOISTED ABOVE the __syncthreads, so the per-block 144 KB W->LDS
// copy (~5-6 us serial start bubble) overlaps the first gathers' HBM
// latency. Depth-3 fixed-stage gather pipeline (B0/B1/B2, refill-after-
// consume, zero extra regs). Plain f32x4 stores (NT slower: R4/R14).
// Unrolled tile loop + per-tile raw s_barrier (load-bearing: R13).
// No cross-seam live state (R6/R7 spill lesson).
__global__ __launch_bounds__(512, 2) void updown_main(
    const u16* __restrict__ xb2, const u16* __restrict__ Wt,
    const int* __restrict__ adjc, const float* __restrict__ bias,
    float* __restrict__ out)
{
    __shared__ __align__(16) u16 wlds[WELEMS];   // 144 KB, read-only after load
    __shared__ __align__(16) float blds[COLS];   // 1 KB bias

    const int tid  = threadIdx.x;
    const int w    = tid >> 6;
    const int lane = tid & 63;
    const int l15  = lane & 15;
    const int q    = lane >> 4;

    const int node0 = blockIdx.x * (TPB * 128) + w * 16 + l15;

    // ---- tile-0 prologue FIRST (no LDS dependence): gathers fly while
    // the W copy + barrier proceed underneath ----
    const int* arow0 = adjc + (size_t)node0 * 9;
    int i0 = arow0[0];
    int i1 = arow0[1];
    int i2 = arow0[2];
    const u16* p0 = xb2 + (size_t)i0 * 64 + q * 8;
    const u16* p1 = xb2 + (size_t)i1 * 64 + q * 8;
    const u16* p2 = xb2 + (size_t)i2 * 64 + q * 8;
    bf16x8 B0t0 = *(const bf16x8*)p0, B0t1 = *(const bf16x8*)(p0 + 32);
    bf16x8 B1t0 = *(const bf16x8*)p1, B1t1 = *(const bf16x8*)(p1 + 32);
    bf16x8 B2t0 = *(const bf16x8*)p2, B2t1 = *(const bf16x8*)(p2 + 32);
    int idxP = arow0[3];

    // ---- W + bias -> LDS (cooperative, coalesced) ----
    #pragma unroll
    for (int i = 0; i < 18; ++i)
        *(bf16x8*)(wlds + i * 4096 + tid * 8) =
            *(const bf16x8*)(Wt + i * 4096 + tid * 8);
    if (tid < 64) ((f32x4*)blds)[tid] = ((const f32x4*)bias)[tid];
    __syncthreads();   // the only full barrier

    const u16* wbase = wlds + lane * 8;   // + kk*8192 + ct*512
    const float* bb  = blds + q * 4;      // + ct*16

    for (int tt = 0; tt < TPB; ++tt) {
        const int node  = node0 + tt * 128;
        const int* arow = adjc + (size_t)node * 9;

        if (tt > 0) {   // tiles 1..5: fresh prologue (tile 0 preloaded)
            int j0 = arow[0];
            int j1 = arow[1];
            int j2 = arow[2];
            const u16* r0 = xb2 + (size_t)j0 * 64 + q * 8;
            const u16* r1 = xb2 + (size_t)j1 * 64 + q * 8;
            const u16* r2 = xb2 + (size_t)j2 * 64 + q * 8;
            B0t0 = *(const bf16x8*)r0; B0t1 = *(const bf16x8*)(r0 + 32);
            B1t0 = *(const bf16x8*)r1; B1t1 = *(const bf16x8*)(r1 + 32);
            B2t0 = *(const bf16x8*)r2; B2t1 = *(const bf16x8*)(r2 + 32);
            idxP = arow[3];
        }

        // acc init = bias (lgkm counter — doesn't touch the vmcnt FIFO)
        f32x4 acc0[16], acc1[16];
        #pragma unroll
        for (int ct = 0; ct < 16; ++ct) {
            f32x4 bq = *(const f32x4*)(bb + ct * 16);
            acc0[ct] = bq;
            acc1[ct] = bq;
        }

        #pragma unroll
        for (int kk = 0; kk < 9; ++kk) {
            const int st = kk % 3;   // compile-time under full unroll
            bf16x8 a0 = (st == 0) ? B0t0 : (st == 1) ? B1t0 : B2t0;
            bf16x8 a1 = (st == 0) ? B0t1 : (st == 1) ? B1t1 : B2t1;

            const u16* wk = wbase + kk * 8192;
            #pragma unroll
            for (int ct = 0; ct < 16; ++ct) {
                bf16x8 af = *(const bf16x8*)(wk + ct * 512);
                acc0[ct] = __builtin_amdgcn_mfma_f32_16x16x32_bf16(af, a0, acc0[ct], 0, 0, 0);
                acc1[ct] = __builtin_amdgcn_mfma_f32_16x16x32_bf16(af, a1, acc1[ct], 0, 0, 0);
            }

            // refill the just-consumed stage for step kk+3
            if (kk < 6) {
                const u16* g2 = xb2 + (size_t)idxP * 64 + q * 8;
                bf16x8 n0 = *(const bf16x8*)g2;
                bf16x8 n1 = *(const bf16x8*)(g2 + 32);
                if      (st == 0) { B0t0 = n0; B0t1 = n1; }
                else if (st == 1) { B1t0 = n0; B1t1 = n1; }
                else              { B2t0 = n0; B2t1 = n1; }
            }
            if (kk < 5) idxP = arow[kk + 4];
        }

        // stores: lane-contiguous f32x4, dense full-line coverage
        float* o0 = out + (size_t)node * COLS + q * 4;
        float* o1 = o0 + (size_t)NNODE * COLS;
        #pragma unroll
        for (int ct = 0; ct < 16; ++ct) {
            *(f32x4*)(o0 + ct * 16) = acc0[ct];
            *(f32x4*)(o1 + ct * 16) = acc1[ct];
        }

        // phase-lock the 8 waves; raw barrier: NO vmcnt drain
        __builtin_amdgcn_s_barrier();
    }
}

extern "C" void kernel_launch(void* const* d_in, const int* in_sizes, int n_in,
                              void* d_out, int out_size, void* d_ws, size_t ws_size,
                              hipStream_t stream) {
    const float* x    = (const float*)d_in[0];
    const int*   adjc = (const int*)d_in[1];
    const float* W    = (const float*)d_in[2];
    const float* b    = (const float*)d_in[3];
    float* out = (float*)d_out;

    u16* xb2 = (u16*)d_ws;                           // 196608*64 bf16 = 25.2 MB
    u16* Wt  = xb2 + (size_t)NNODE * 64;             // 73728 bf16 = 144 KB

    prep<<<dim3(XBLKS + 288), dim3(256), 0, stream>>>(x, xb2, W, Wt);
    updown_main<<<dim3(256), dim3(512), 0, stream>>>(xb2, Wt, adjc, b, out);
}